// Round 2
// baseline (177.897 us; speedup 1.0000x reference)
//
#include <hip/hip_runtime.h>

// Problem constants (fixed by setup_inputs)
constexpr int kB  = 4;
constexpr int kNp = 8192;
constexpr int kNq = 2048;
constexpr int kK  = 32;   // max samples per query
constexpr float kR2 = (float)(0.2 * 0.2);   // matches numpy f32(radius*radius)

typedef float v4f __attribute__((ext_vector_type(4)));
typedef int   v4i __attribute__((ext_vector_type(4)));

// ---------------------------------------------------------------------------
// Kernel A: coords [B][Np][3] -> SoA cb3 [B][3][Np].
// v2: one thread per 4 points. Three dwordx4 loads cover 48 contiguous bytes
// per lane (wave reads a contiguous 3 KB span, every line fully consumed);
// x/y/z of points 4l..4l+3 all live inside lane l's 12 dwords, so the
// transpose is pure in-register swizzle (no LDS, no shuffles). SoA writes
// are dwordx4 coalesced. Grid: 32 blocks.
// ---------------------------------------------------------------------------
__global__ __launch_bounds__(256) void coords_soa_kernel(
    const float* __restrict__ coords, float* __restrict__ cb3)
{
    const int t  = blockIdx.x * 256 + threadIdx.x;   // 0 .. B*Np/4-1
    const int b  = t >> 11;                          // / (Np/4)
    const int p4 = t & (kNp / 4 - 1);                // 4-point group

    const v4f* c4 = (const v4f*)(coords + (size_t)b * kNp * 3 + (size_t)p4 * 12);
    const v4f d0 = c4[0];   // x0 y0 z0 x1
    const v4f d1 = c4[1];   // y1 z1 x2 y2
    const v4f d2 = c4[2];   // z2 x3 y3 z3

    v4f X = {d0.x, d0.w, d1.z, d2.y};
    v4f Y = {d0.y, d1.x, d1.w, d2.z};
    v4f Z = {d0.z, d1.y, d2.x, d2.w};

    float* o = cb3 + (size_t)b * 3 * kNp;
    ((v4f*)(o + 0 * kNp))[p4] = X;
    ((v4f*)(o + 1 * kNp))[p4] = Y;
    ((v4f*)(o + 2 * kNp))[p4] = Z;
}

// ---------------------------------------------------------------------------
// Kernel B: ball query, one wave per query (unchanged from verified round-1
// version: chunk-ahead load pipelining, exact f32 arithmetic, uniform
// 256-point early exit, NT coord-channel stores).
// ---------------------------------------------------------------------------
__global__ __launch_bounds__(256) void ball_query_kernel(
    const float* __restrict__ cb3,      // [B][3][Np]
    const float* __restrict__ queries,  // [B][Nq][3]
    int* __restrict__ idxs,             // [B*Nq][K] (resolved, fill applied)
    float* __restrict__ out)            // full output tensor
{
    const int wave = (int)((blockIdx.x * blockDim.x + threadIdx.x) >> 6);
    const int lane = threadIdx.x & 63;
    const int w    = threadIdx.x >> 6;          // wave within block (0..3)
    const int b    = wave >> 11;                // / Nq
    const int q    = wave & (kNq - 1);

    const float qx = queries[(b * kNq + q) * 3 + 0];
    const float qy = queries[(b * kNq + q) * 3 + 1];
    const float qz = queries[(b * kNq + q) * 3 + 2];

    const float* __restrict__ cbx = cb3 + (size_t)b * 3 * kNp;
    const float* __restrict__ cby = cbx + kNp;
    const float* __restrict__ cbz = cby + kNp;
    const v4f* __restrict__ cbx4 = (const v4f*)cbx;
    const v4f* __restrict__ cby4 = (const v4f*)cby;
    const v4f* __restrict__ cbz4 = (const v4f*)cbz;

    __shared__ int s_idx[4][kK];   // per-wave private region; no barrier needed

    const unsigned long long lt = (1ull << lane) - 1ull;
    int cnt = 0;

    // prologue: load chunk 0
    v4f X = cbx4[lane];
    v4f Y = cby4[lane];
    v4f Z = cbz4[lane];

    for (int base = 0; base < kNp; base += 256) {
        // prefetch chunk base+256 (clamped in-bounds; unused on exit/wrap)
        const int nvi = (base + 256 < kNp) ? (((base + 256) >> 2) + lane) : lane;
        const v4f Xn = cbx4[nvi];
        const v4f Yn = cby4[nvi];
        const v4f Zn = cbz4[nvi];

        bool in[4];
        unsigned long long m[4];
#pragma unroll
        for (int j = 0; j < 4; ++j) {
            // exact f32 per-op arithmetic (no fma contraction) to match numpy
            const float dx = __fsub_rn(qx, X[j]);
            const float dy = __fsub_rn(qy, Y[j]);
            const float dz = __fsub_rn(qz, Z[j]);
            const float d2 = __fadd_rn(
                __fadd_rn(__fmul_rn(dx, dx), __fmul_rn(dy, dy)),
                __fmul_rn(dz, dz));
            in[j] = d2 < kR2;
            m[j] = __ballot(in[j]);
        }

        // point index = base + 4*lane + j (lane-major)
        int pre = cnt + __popcll(m[0] & lt) + __popcll(m[1] & lt)
                      + __popcll(m[2] & lt) + __popcll(m[3] & lt);
        int local = 0;
#pragma unroll
        for (int j = 0; j < 4; ++j) {
            if (in[j]) {
                const int slot = pre + local;
                if (slot < kK) s_idx[w][slot] = base + 4 * lane + j;
                ++local;
            }
        }
        cnt += __popcll(m[0]) + __popcll(m[1])
             + __popcll(m[2]) + __popcll(m[3]);     // wave-uniform

        X = Xn; Y = Yn; Z = Zn;
        if (cnt >= kK) break;                       // uniform branch
    }

    if (lane < kK) {
        int v;
        if (cnt == 0)        v = 0;
        else if (lane < cnt) v = s_idx[w][lane];
        else                 v = s_idx[w][0];       // fill with first valid
        idxs[(size_t)wave * kK + lane] = v;

        // centered-coords output channels 0..2 (NT: write-once stream)
        const int k = lane;
        float* gf = out + ((size_t)(b * 67) * kNq + q) * kK + k;
        __builtin_nontemporal_store(__fsub_rn(cbx[v], qx), gf + (size_t)0 * kNq * kK);
        __builtin_nontemporal_store(__fsub_rn(cby[v], qy), gf + (size_t)1 * kNq * kK);
        __builtin_nontemporal_store(__fsub_rn(cbz[v], qz), gf + (size_t)2 * kNq * kK);
    }
}

// ---------------------------------------------------------------------------
// Kernel C: scatter-free gather. v3 changes:
//  (a) depth-8 software pipeline on idx loads: preload 8 v4i groups, then
//      4 passes of {consume 8, prefetch next 8}. All array indices are
//      compile-time (full unroll) so id[] stays in registers (no scratch).
//      Doubles idx-load MLP vs the previous implicit unroll-4.
//  (b) row staging back to cached loads (each row is read by the 2
//      half-blocks; L2 serves the second one).
//  Output stores remain non-temporal (131 MB write-once stream; keeps idx
//  and rows L2-resident).
// ---------------------------------------------------------------------------
__global__ __launch_bounds__(256) void gather_kernel(
    const float* __restrict__ feat,   // [B][64][Np]
    const float* __restrict__ temb,   // [B][64][Np]
    const int*   __restrict__ idxs,   // [B*Nq][K] resolved
    float* __restrict__ out)
{
    const int blk = blockIdx.x;        // 0 .. 1023
    const int seg = blk & 1;           // query half
    const int bc  = blk >> 1;          // 0 .. 511
    const int b   = bc >> 7;
    const int j   = bc & 127;          // 0..63 feat, 64..127 temb

    const float* src;
    float* dst;
    if (j < 64) {
        src = feat + ((size_t)b * 64 + j) * kNp;
        dst = out + (size_t)(b * 67 + 3 + j) * (kNq * kK);
    } else {
        src = temb + ((size_t)b * 64 + (j - 64)) * kNp;
        dst = out + (size_t)kB * 67 * kNq * kK
                  + (size_t)(b * 64 + (j - 64)) * (kNq * kK);
    }

    __shared__ float row[kNp];         // 32 KB
    {
        const v4f* s4 = (const v4f*)src;
        v4f* r4 = (v4f*)row;
#pragma unroll
        for (int i = 0; i < kNp / 4 / 256; ++i)     // 8 iters
            r4[i * 256 + threadIdx.x] = s4[i * 256 + threadIdx.x];
    }
    __syncthreads();

    constexpr int total4 = kNq * kK / 4;            // 16384
    constexpr int seg4   = total4 / 2;              // 8192 per half
    const v4i* id4 = (const v4i*)(idxs + (size_t)b * kNq * kK) + seg * seg4;
    v4f* d4 = (v4f*)dst + seg * seg4;
    const int e0 = threadIdx.x;                     // 32 groups: e0 + g*256

    v4i id[8];
#pragma unroll
    for (int g = 0; g < 8; ++g)
        id[g] = id4[e0 + g * 256];

#pragma unroll
    for (int pass = 0; pass < 4; ++pass) {
#pragma unroll
        for (int g = 0; g < 8; ++g) {
            const v4i cur = id[g];
            if (pass < 3)                            // compile-time per copy
                id[g] = id4[e0 + ((pass + 1) * 8 + g) * 256];
            v4f v;
            v.x = row[cur.x];
            v.y = row[cur.y];
            v.z = row[cur.z];
            v.w = row[cur.w];
            __builtin_nontemporal_store(v, d4 + e0 + (pass * 8 + g) * 256);
        }
    }
}

// ---------------------------------------------------------------------------
extern "C" void kernel_launch(void* const* d_in, const int* in_sizes, int n_in,
                              void* d_out, int out_size, void* d_ws, size_t ws_size,
                              hipStream_t stream) {
    const float* coords  = (const float*)d_in[0];  // [B,Np,3]
    const float* feats   = (const float*)d_in[1];  // [B,64,Np]
    const float* temb    = (const float*)d_in[2];  // [B,64,Np]
    const float* queries = (const float*)d_in[3];  // [B,Nq,3]
    float* out = (float*)d_out;

    int*   idxs = (int*)d_ws;                                          // 1 MB
    float* cb3  = (float*)((char*)d_ws + (size_t)kB * kNq * kK * 4);   // 384 KB

    coords_soa_kernel<<<kB * kNp / 4 / 256, 256, 0, stream>>>(coords, cb3);
    ball_query_kernel<<<kB * kNq / 4, 256, 0, stream>>>(cb3, queries, idxs, out);
    gather_kernel<<<kB * 128 * 2, 256, 0, stream>>>(feats, temb, idxs, out);
}

// Round 3
// 177.305 us; speedup vs baseline: 1.0033x; 1.0033x over previous
//
#include <hip/hip_runtime.h>

// Problem constants (fixed by setup_inputs)
constexpr int kB  = 4;
constexpr int kNp = 8192;
constexpr int kNq = 2048;
constexpr int kK  = 32;   // max samples per query
constexpr float kR2 = (float)(0.2 * 0.2);   // matches numpy f32(radius*radius)

typedef float        v4f __attribute__((ext_vector_type(4)));
typedef int          v4i __attribute__((ext_vector_type(4)));
typedef unsigned int v2u __attribute__((ext_vector_type(2)));

// ---------------------------------------------------------------------------
// Kernel A: coords [B][Np][3] -> SoA cb3 [B][3][Np]. One thread per 4 points:
// three dwordx4 loads cover a contiguous 48 B/lane (wave = 3 KB span, every
// line fully consumed); transpose is in-register swizzle; dwordx4 SoA writes.
// ---------------------------------------------------------------------------
__global__ __launch_bounds__(256) void coords_soa_kernel(
    const float* __restrict__ coords, float* __restrict__ cb3)
{
    const int t  = blockIdx.x * 256 + threadIdx.x;   // 0 .. B*Np/4-1
    const int b  = t >> 11;                          // / (Np/4)
    const int p4 = t & (kNp / 4 - 1);                // 4-point group

    const v4f* c4 = (const v4f*)(coords + (size_t)b * kNp * 3 + (size_t)p4 * 12);
    const v4f d0 = c4[0];   // x0 y0 z0 x1
    const v4f d1 = c4[1];   // y1 z1 x2 y2
    const v4f d2 = c4[2];   // z2 x3 y3 z3

    v4f X = {d0.x, d0.w, d1.z, d2.y};
    v4f Y = {d0.y, d1.x, d1.w, d2.z};
    v4f Z = {d0.z, d1.y, d2.x, d2.w};

    float* o = cb3 + (size_t)b * 3 * kNp;
    ((v4f*)(o + 0 * kNp))[p4] = X;
    ((v4f*)(o + 1 * kNp))[p4] = Y;
    ((v4f*)(o + 2 * kNp))[p4] = Z;
}

// ---------------------------------------------------------------------------
// Kernel B: ball query, TWO queries per wave (qa = 2*wq, qb = 2*wq+1).
// The 256-point coord chunk (3 dwordx4 loads, prefetched one chunk ahead) is
// shared by the pair -> coord L2 traffic drops ~34% (pair scans max(c0,c1)
// chunks instead of c0+c1). A finished query's ballot/slot block is skipped
// by a wave-uniform branch, so per-query distance arithmetic and the
// first-K-in-index-order selection are bit-identical to the verified kernel
// (overscan slot writes are slot<kK-guarded out). Epilogue: all 64 lanes
// active; idx (u16) + 3 centered-coord channels are fully coalesced
// wave-stores covering both queries of the pair.
// ---------------------------------------------------------------------------
__global__ __launch_bounds__(256) void ball_query_kernel(
    const float* __restrict__ cb3,      // [B][3][Np]
    const float* __restrict__ queries,  // [B][Nq][3]
    unsigned short* __restrict__ idxs,  // [B*Nq][K] u16, resolved (fill applied)
    float* __restrict__ out)            // full output tensor
{
    const int wq   = (int)((blockIdx.x * blockDim.x + threadIdx.x) >> 6); // 0..4095
    const int lane = threadIdx.x & 63;
    const int w    = threadIdx.x >> 6;          // wave within block (0..3)
    const int b    = wq >> 10;                  // / (Nq/2)
    const int qa   = (wq & (kNq / 2 - 1)) * 2;  // first query of the pair

    const float* qp = queries + ((size_t)b * kNq + qa) * 3;
    const float qx0 = qp[0], qy0 = qp[1], qz0 = qp[2];
    const float qx1 = qp[3], qy1 = qp[4], qz1 = qp[5];

    const float* __restrict__ cbx = cb3 + (size_t)b * 3 * kNp;
    const float* __restrict__ cby = cbx + kNp;
    const float* __restrict__ cbz = cby + kNp;
    const v4f* __restrict__ cbx4 = (const v4f*)cbx;
    const v4f* __restrict__ cby4 = (const v4f*)cby;
    const v4f* __restrict__ cbz4 = (const v4f*)cbz;

    __shared__ int s_idx[4][2][kK];   // per-wave private region; no barrier needed

    const unsigned long long lt = (1ull << lane) - 1ull;
    int cnt0 = 0, cnt1 = 0;

    // prologue: load chunk 0
    v4f X = cbx4[lane];
    v4f Y = cby4[lane];
    v4f Z = cbz4[lane];

    for (int base = 0; base < kNp; base += 256) {
        // prefetch chunk base+256 (clamped in-bounds; unused on exit/wrap)
        const int nvi = (base + 256 < kNp) ? (((base + 256) >> 2) + lane) : lane;
        const v4f Xn = cbx4[nvi];
        const v4f Yn = cby4[nvi];
        const v4f Zn = cbz4[nvi];

        if (cnt0 < kK) {            // wave-uniform (cnt0 from ballots)
            bool in[4];
            unsigned long long m[4];
#pragma unroll
            for (int j = 0; j < 4; ++j) {
                // exact f32 per-op arithmetic (no fma contraction)
                const float dx = __fsub_rn(qx0, X[j]);
                const float dy = __fsub_rn(qy0, Y[j]);
                const float dz = __fsub_rn(qz0, Z[j]);
                const float d2 = __fadd_rn(
                    __fadd_rn(__fmul_rn(dx, dx), __fmul_rn(dy, dy)),
                    __fmul_rn(dz, dz));
                in[j] = d2 < kR2;
                m[j] = __ballot(in[j]);
            }
            int pre = cnt0 + __popcll(m[0] & lt) + __popcll(m[1] & lt)
                           + __popcll(m[2] & lt) + __popcll(m[3] & lt);
            int local = 0;
#pragma unroll
            for (int j = 0; j < 4; ++j) {
                if (in[j]) {
                    const int slot = pre + local;
                    if (slot < kK) s_idx[w][0][slot] = base + 4 * lane + j;
                    ++local;
                }
            }
            cnt0 += __popcll(m[0]) + __popcll(m[1])
                  + __popcll(m[2]) + __popcll(m[3]);     // wave-uniform
        }

        if (cnt1 < kK) {            // wave-uniform
            bool in[4];
            unsigned long long m[4];
#pragma unroll
            for (int j = 0; j < 4; ++j) {
                const float dx = __fsub_rn(qx1, X[j]);
                const float dy = __fsub_rn(qy1, Y[j]);
                const float dz = __fsub_rn(qz1, Z[j]);
                const float d2 = __fadd_rn(
                    __fadd_rn(__fmul_rn(dx, dx), __fmul_rn(dy, dy)),
                    __fmul_rn(dz, dz));
                in[j] = d2 < kR2;
                m[j] = __ballot(in[j]);
            }
            int pre = cnt1 + __popcll(m[0] & lt) + __popcll(m[1] & lt)
                           + __popcll(m[2] & lt) + __popcll(m[3] & lt);
            int local = 0;
#pragma unroll
            for (int j = 0; j < 4; ++j) {
                if (in[j]) {
                    const int slot = pre + local;
                    if (slot < kK) s_idx[w][1][slot] = base + 4 * lane + j;
                    ++local;
                }
            }
            cnt1 += __popcll(m[0]) + __popcll(m[1])
                  + __popcll(m[2]) + __popcll(m[3]);
        }

        X = Xn; Y = Yn; Z = Zn;
        if (cnt0 >= kK && cnt1 >= kK) break;        // uniform branch
    }

    // Epilogue: lanes 0..31 -> qa slot k=lane; lanes 32..63 -> qb slot k=lane-32.
    // Flat element offset qa*kK + lane covers both halves contiguously.
    const int half = lane >> 5;
    const int k    = lane & (kK - 1);
    const int cnt  = half ? cnt1 : cnt0;
    int v;
    if (cnt == 0)     v = 0;
    else if (k < cnt) v = s_idx[w][half][k];
    else              v = s_idx[w][half][0];        // fill with first valid

    idxs[((size_t)(b * kNq + qa)) * kK + lane] = (unsigned short)v;

    const float qxh = half ? qx1 : qx0;
    const float qyh = half ? qy1 : qy0;
    const float qzh = half ? qz1 : qz0;
    float* gf = out + ((size_t)(b * 67) * kNq + qa) * kK + lane;
    __builtin_nontemporal_store(__fsub_rn(cbx[v], qxh), gf + (size_t)0 * kNq * kK);
    __builtin_nontemporal_store(__fsub_rn(cby[v], qyh), gf + (size_t)1 * kNq * kK);
    __builtin_nontemporal_store(__fsub_rn(cbz[v], qzh), gf + (size_t)2 * kNq * kK);
}

// ---------------------------------------------------------------------------
// Kernel C: scatter-free gather. v4: u16 indices (halved idx L2 traffic,
// 512 KB total footprint -> fully L2-resident). Depth-8 idx pipeline kept
// (all compile-time indices -> registers). Output stores non-temporal
// (131 MB write-once stream stays out of L2).
// ---------------------------------------------------------------------------
__global__ __launch_bounds__(256) void gather_kernel(
    const float* __restrict__ feat,            // [B][64][Np]
    const float* __restrict__ temb,            // [B][64][Np]
    const unsigned short* __restrict__ idxs,   // [B*Nq][K] u16 resolved
    float* __restrict__ out)
{
    const int blk = blockIdx.x;        // 0 .. 1023
    const int seg = blk & 1;           // query half
    const int bc  = blk >> 1;          // 0 .. 511
    const int b   = bc >> 7;
    const int j   = bc & 127;          // 0..63 feat, 64..127 temb

    const float* src;
    float* dst;
    if (j < 64) {
        src = feat + ((size_t)b * 64 + j) * kNp;
        dst = out + (size_t)(b * 67 + 3 + j) * (kNq * kK);
    } else {
        src = temb + ((size_t)b * 64 + (j - 64)) * kNp;
        dst = out + (size_t)kB * 67 * kNq * kK
                  + (size_t)(b * 64 + (j - 64)) * (kNq * kK);
    }

    __shared__ float row[kNp];         // 32 KB
    {
        const v4f* s4 = (const v4f*)src;
        v4f* r4 = (v4f*)row;
#pragma unroll
        for (int i = 0; i < kNp / 4 / 256; ++i)     // 8 iters
            r4[i * 256 + threadIdx.x] = s4[i * 256 + threadIdx.x];
    }
    __syncthreads();

    constexpr int total4 = kNq * kK / 4;            // 16384 4-index groups
    constexpr int seg4   = total4 / 2;              // 8192 per half
    // each v2u = 8 B = 4 packed u16 indices
    const v2u* id2 = (const v2u*)(idxs + (size_t)b * kNq * kK) + seg * seg4;
    v4f* d4 = (v4f*)dst + seg * seg4;
    const int e0 = threadIdx.x;                     // 32 groups: e0 + g*256

    v2u id[8];
#pragma unroll
    for (int g = 0; g < 8; ++g)
        id[g] = id2[e0 + g * 256];

#pragma unroll
    for (int pass = 0; pass < 4; ++pass) {
#pragma unroll
        for (int g = 0; g < 8; ++g) {
            const v2u cur = id[g];
            if (pass < 3)                            // compile-time per copy
                id[g] = id2[e0 + ((pass + 1) * 8 + g) * 256];
            v4f v;
            v.x = row[cur.x & 0xffffu];
            v.y = row[cur.x >> 16];
            v.z = row[cur.y & 0xffffu];
            v.w = row[cur.y >> 16];
            __builtin_nontemporal_store(v, d4 + e0 + (pass * 8 + g) * 256);
        }
    }
}

// ---------------------------------------------------------------------------
extern "C" void kernel_launch(void* const* d_in, const int* in_sizes, int n_in,
                              void* d_out, int out_size, void* d_ws, size_t ws_size,
                              hipStream_t stream) {
    const float* coords  = (const float*)d_in[0];  // [B,Np,3]
    const float* feats   = (const float*)d_in[1];  // [B,64,Np]
    const float* temb    = (const float*)d_in[2];  // [B,64,Np]
    const float* queries = (const float*)d_in[3];  // [B,Nq,3]
    float* out = (float*)d_out;

    unsigned short* idxs = (unsigned short*)d_ws;                      // 512 KB
    float* cb3 = (float*)((char*)d_ws + (size_t)kB * kNq * kK * 2);    // 384 KB

    coords_soa_kernel<<<kB * kNp / 4 / 256, 256, 0, stream>>>(coords, cb3);
    ball_query_kernel<<<kB * kNq / 8, 256, 0, stream>>>(cb3, queries, idxs, out);
    gather_kernel<<<kB * 128 * 2, 256, 0, stream>>>(feats, temb, idxs, out);
}